// Round 3
// baseline (535.662 us; speedup 1.0000x reference)
//
#include <hip/hip_runtime.h>
#include <hip/hip_fp16.h>

// ComplexFaberConv: degree-normalized directed SpMM + collapsed complex linear.
//
// Math (linear in k, so W-stacks collapse):
//   WrE = sum_k 0.5^k W_real[k], WiE likewise; brE, biE likewise.
//   u = y_real, v = y_real_t, S = y_imag + y_imag_t
//   total_real = 0.5*(u+v)@WrE^T - 0.5*S@WiE^T + (brE-biE)
//   total_imag = u@WiE^T + 0.5*S@WrE^T + (brE+biE)
// (reference faithfully uses y_real, not y_real_t, in sum_imag_d2s)
//
// R6: bucket partition (196 buckets of 512 nodes) for degree+fill.
// R7: split VALU matvec epilogue into MFMA gemm_kernel (gather 211 -> 124 us).
// R8: single unscaled xp array, per-edge inv scale packed in idx bits
//     (gather 124 -> 113 us; L2-churn-limited at ~56% hit, structural).
// R9 (this round): delete the Apack global round-trip (37.5 MB write + 37.5 MB
// read) and the separate gemm dispatch by fusing the MFMA epilogue into the
// gather kernel. Per wave: gather 16 nodes (one MFMA M-tile), stage reduced
// rows into a 6 KB XOR-swizzled per-wave LDS tile (wave-synchronous RAW),
// then 32x mfma_f32_16x16x32_f16 with B-fragments loaded from global (32 KB,
// L2-resident; LDS stays 24 KB/block -> 6 blocks/CU). Tiles are handed out by
// a global atomic counter for dynamic load balance.

constexpr int D = 64;
constexpr int SB = 256;   // scan elements per block
constexpr int G1 = 256;   // partition blocks

typedef _Float16 f16x8 __attribute__((ext_vector_type(8)));
typedef float f32x4 __attribute__((ext_vector_type(4)));

__device__ __forceinline__ float2 h2_to_f2(uint p) {
  __half2 h = *(__half2*)&p;
  return __half22float2(h);
}

// ---------- partition phase ----------

// Per-block bucket histograms: h[bucket*G1 + block]. bucket = node>>9.
__global__ __launch_bounds__(256) void part_count(
    const int* __restrict__ row, const int* __restrict__ col,
    int* __restrict__ hout, int* __restrict__ hin, int E, int NBUK, int CH) {
  __shared__ int ho[256], hi_[256];
  int t = threadIdx.x, g = blockIdx.x;
  ho[t] = 0;
  hi_[t] = 0;
  __syncthreads();
  int e0 = g * CH, e1 = min(E, e0 + CH);
  for (int e = e0 + t; e < e1; e += 256) {
    atomicAdd(&ho[row[e] >> 9], 1);
    atomicAdd(&hi_[col[e] >> 9], 1);
  }
  __syncthreads();
  if (t < NBUK) {
    hout[t * G1 + g] = ho[t];
    hin[t * G1 + g] = hi_[t];
  }
}

// Scatter edges into block-exclusive per-bucket ranges (LDS cursors only).
// pack = (node_local<<17) | neighbor  (node_local<512 -> 9b, neighbor<131072 -> 17b)
__global__ __launch_bounds__(256) void part_scatter(
    const int* __restrict__ row, const int* __restrict__ col,
    const int* __restrict__ hout, const int* __restrict__ hin,
    uint* __restrict__ pout, uint* __restrict__ pin, int E, int NBUK, int CH) {
  __shared__ int co[256], ci[256];
  int t = threadIdx.x, g = blockIdx.x;
  if (t < NBUK) {
    co[t] = hout[t * G1 + g];
    ci[t] = hin[t * G1 + g];
  }
  __syncthreads();
  int e0 = g * CH, e1 = min(E, e0 + CH);
  for (int e = e0 + t; e < e1; e += 256) {
    int r = row[e], c = col[e];
    int po = atomicAdd(&co[r >> 9], 1);
    pout[po] = ((uint)(r & 511) << 17) | (uint)c;
    int pi = atomicAdd(&ci[c >> 9], 1);
    pin[pi] = ((uint)(c & 511) << 17) | (uint)r;
  }
}

// One block per bucket: LDS degree histogram -> coalesced global deg write.
__global__ __launch_bounds__(256) void bucket_degree(
    const uint* __restrict__ pout, const uint* __restrict__ pin,
    const int* __restrict__ hout, const int* __restrict__ hin,
    int* __restrict__ deg_out, int* __restrict__ deg_in, int E, int NBUK, int N) {
  const uint* p = blockIdx.y ? pin : pout;
  const int* h = blockIdx.y ? hin : hout;
  int* deg = blockIdx.y ? deg_in : deg_out;
  __shared__ int ld[512];
  int t = threadIdx.x, b = blockIdx.x;
  ld[t] = 0;
  ld[t + 256] = 0;
  __syncthreads();
  int s = h[b * G1];
  int e = (b + 1 < NBUK) ? h[(b + 1) * G1] : E;
  for (int j = s + t; j < e; j += 256) atomicAdd(&ld[p[j] >> 17], 1);
  __syncthreads();
  int n0 = (b << 9) + t;
  if (n0 < N) deg[n0] = ld[t];
  if (n0 + 256 < N) deg[n0 + 256] = ld[t + 256];
}

// One block per bucket: LDS cursors seeded from ofs; idx window is block-private.
// idx entry = (f16bits(inv_of_neighbor)<<17) | neighbor. y=0: pout->idx_out,
// neighbors are cols -> inv_in; y=1: pin->idx_in, neighbors are rows -> inv_out.
__global__ __launch_bounds__(256) void bucket_fill(
    const uint* __restrict__ pout, const uint* __restrict__ pin,
    const int* __restrict__ hout, const int* __restrict__ hin,
    const int* __restrict__ ofs_out, const int* __restrict__ ofs_in,
    const float* __restrict__ inv_out, const float* __restrict__ inv_in,
    uint* __restrict__ idx_out, uint* __restrict__ idx_in, int E, int NBUK, int N) {
  const uint* p = blockIdx.y ? pin : pout;
  const int* h = blockIdx.y ? hin : hout;
  const int* ofs = blockIdx.y ? ofs_in : ofs_out;
  const float* invnb = blockIdx.y ? inv_out : inv_in;
  uint* idx = blockIdx.y ? idx_in : idx_out;
  __shared__ int cur[512];
  int t = threadIdx.x, b = blockIdx.x;
  int n0 = (b << 9) + t;
  cur[t] = (n0 < N) ? ofs[n0] : 0;
  cur[t + 256] = (n0 + 256 < N) ? ofs[n0 + 256] : 0;
  __syncthreads();
  int s = h[b * G1];
  int e = (b + 1 < NBUK) ? h[(b + 1) * G1] : E;
  for (int j = s + t; j < e; j += 256) {
    uint pk = p[j];
    uint nbr = pk & 0x1FFFFu;
    uint hb = (uint)__half_as_ushort(__float2half(invnb[nbr]));  // <= 0x3C00
    int pos = atomicAdd(&cur[pk >> 17], 1);
    idx[pos] = (hb << 17) | nbr;
  }
}

// ---------- scans ----------

// Phase 1: per-block sums of two arrays. grid=(NB,2).
__global__ __launch_bounds__(SB) void bsum_kernel(
    const int* __restrict__ a0, const int* __restrict__ a1,
    int* __restrict__ bsum, int n, int NB) {
  const int* a = blockIdx.y ? a1 : a0;
  int i = blockIdx.x * SB + threadIdx.x;
  int d = (i < n) ? a[i] : 0;
#pragma unroll
  for (int m = 1; m < 64; m <<= 1) d += __shfl_xor(d, m);
  __shared__ int ws[SB / 64];
  if ((threadIdx.x & 63) == 0) ws[threadIdx.x >> 6] = d;
  __syncthreads();
  if (threadIdx.x == 0) {
    int s = 0;
#pragma unroll
    for (int w = 0; w < SB / 64; ++w) s += ws[w];
    bsum[blockIdx.y * NB + blockIdx.x] = s;
  }
}

// Phase 2: exclusive scan of both NB-entry segments (NB <= 1024), 1 block.
__global__ __launch_bounds__(1024) void bscan_kernel(int* __restrict__ bsum, int NB) {
  __shared__ int s0[1024], s1[1024];
  int t = threadIdx.x;
  int o0 = (t < NB) ? bsum[t] : 0;
  int o1 = (t < NB) ? bsum[NB + t] : 0;
  s0[t] = o0;
  s1[t] = o1;
  __syncthreads();
  for (int off = 1; off < 1024; off <<= 1) {
    int v0 = (t >= off) ? s0[t - off] : 0;
    int v1 = (t >= off) ? s1[t - off] : 0;
    __syncthreads();
    s0[t] += v0;
    s1[t] += v1;
    __syncthreads();
  }
  if (t < NB) {
    bsum[t] = s0[t] - o0;  // exclusive
    bsum[NB + t] = s1[t] - o1;
  }
}

// Phase 3 (generic, in-place): exclusive scan finalize for the histograms.
__global__ __launch_bounds__(SB) void gfin_kernel(
    int* __restrict__ h0, int* __restrict__ h1,
    const int* __restrict__ bsum, int n, int NB) {
  int* h = blockIdx.y ? h1 : h0;
  int base = bsum[blockIdx.y * NB + blockIdx.x];
  int lane = threadIdx.x & 63, wv = threadIdx.x >> 6;
  int i = blockIdx.x * SB + threadIdx.x;
  int d = (i < n) ? h[i] : 0;
  int sc = d;
#pragma unroll
  for (int off = 1; off < 64; off <<= 1) {
    int v = __shfl_up(sc, off);
    if (lane >= off) sc += v;
  }
  __shared__ int ws[SB / 64];
  if (lane == 63) ws[wv] = sc;
  __syncthreads();
  int wbase = 0;
#pragma unroll
  for (int w = 0; w < SB / 64; ++w)
    if (w < wv) wbase += ws[w];
  if (i < n) h[i] = base + wbase + (sc - d);
}

// Phase 3 (degrees): exclusive ofs (N+1, [N]=E) + inv = deg^-0.25.
__global__ __launch_bounds__(SB) void sfin_kernel(
    const int* __restrict__ deg_out, const int* __restrict__ deg_in,
    const int* __restrict__ bsum,
    int* __restrict__ ofs_out, int* __restrict__ ofs_in,
    float* __restrict__ inv_out, float* __restrict__ inv_in, int N, int NB) {
  const int* deg = blockIdx.y ? deg_in : deg_out;
  int* ofs = blockIdx.y ? ofs_in : ofs_out;
  float* inv = blockIdx.y ? inv_in : inv_out;
  int base = bsum[blockIdx.y * NB + blockIdx.x];
  int lane = threadIdx.x & 63, wv = threadIdx.x >> 6;
  int i = blockIdx.x * SB + threadIdx.x;
  int d = (i < N) ? deg[i] : 0;
  int sc = d;
#pragma unroll
  for (int off = 1; off < 64; off <<= 1) {
    int v = __shfl_up(sc, off);
    if (lane >= off) sc += v;
  }
  __shared__ int ws[SB / 64];
  if (lane == 63) ws[wv] = sc;
  __syncthreads();
  int wbase = 0;
#pragma unroll
  for (int w = 0; w < SB / 64; ++w)
    if (w < wv) wbase += ws[w];
  if (i < N) {
    ofs[i] = base + wbase + (sc - d);  // exclusive prefix
    inv[i] = d > 0 ? rsqrtf(sqrtf((float)d)) : 0.0f;
  }
  if (i == N - 1) ofs[N] = base + wbase + sc;
}

// ---------- dense prep ----------

// Unscaled packed features: xp[n*64+d] = half2(xr, xi). 25.6 MB, single array
// for both gather directions (scale rides in the idx entries).
__global__ void pack_kernel(const float* __restrict__ xr, const float* __restrict__ xi,
                            uint* __restrict__ xp, int total4) {
  int i = blockIdx.x * blockDim.x + threadIdx.x;  // over N*16 uint4 groups
  if (i < total4) {
    float4 a = ((const float4*)xr)[i];
    float4 b = ((const float4*)xi)[i];
    __half2 h;
    uint4 o;
    h = __floats2half2_rn(a.x, b.x); o.x = *(uint*)&h;
    h = __floats2half2_rn(a.y, b.y); o.y = *(uint*)&h;
    h = __floats2half2_rn(a.z, b.z); o.z = *(uint*)&h;
    h = __floats2half2_rn(a.w, b.w); o.w = *(uint*)&h;
    ((uint4*)xp)[i] = o;
  }
}

// Fused: collapse K=3 weight stacks (LDS-resident Wh) then emit MFMA B-fragments.
//   Bfrag[fr][lane] = 8 f16, fr = ((mat*4+kt)*4+nt), element:
//     k_local = 8*(lane>>4) + j + 32*kt  (0..127),  o = (lane&15) + 16*nt
//     mat 0 (real): k<64 -> wr[k][o], else -wi[k-64][o]
//     mat 1 (imag): k<64 -> wr[k][o], else +wi[k-64][o]
// Also zeroes the dynamic tile counter.
__global__ __launch_bounds__(1024) void wprep_kernel(
    const float* __restrict__ Wr, const float* __restrict__ br,
    const float* __restrict__ Wi, const float* __restrict__ bi,
    uint4* __restrict__ Bfrag, float* __restrict__ cR, float* __restrict__ cI,
    int* __restrict__ tile_ctr) {
  __shared__ uint sWh[4096];  // Wh[d*64+o]
  int t = threadIdx.x;
  if (t == 0) *tile_ctr = 0;
  for (int i = t; i < 4096; i += 1024) {
    int o = i >> 6, d = i & 63;
    float wr = Wr[i] + 0.5f * Wr[4096 + i] + 0.25f * Wr[8192 + i];
    float wi = Wi[i] + 0.5f * Wi[4096 + i] + 0.25f * Wi[8192 + i];
    __half2 h = __floats2half2_rn(wr, wi);
    sWh[d * 64 + o] = *(uint*)&h;
  }
  if (t < 64) {
    float brv = br[t] + 0.5f * br[64 + t] + 0.25f * br[128 + t];
    float biv = bi[t] + 0.5f * bi[64 + t] + 0.25f * bi[128 + t];
    cR[t] = brv - biv;
    cI[t] = brv + biv;
  }
  __syncthreads();
  for (int tt = t; tt < 2048; tt += 1024) {
    int lane = tt & 63, fr = tt >> 6;
    int mat = fr >> 4, kt = (fr >> 2) & 3, nt = fr & 3;
    int o = (lane & 15) + 16 * nt;
    int k0 = 8 * (lane >> 4) + 32 * kt;
    uint wbits[4];
#pragma unroll
    for (int jj = 0; jj < 4; ++jj) {
      float v[2];
#pragma unroll
      for (int s = 0; s < 2; ++s) {
        int k = k0 + 2 * jj + s;
        float2 wrwi = h2_to_f2(sWh[(k & 63) * 64 + o]);
        v[s] = (k < 64) ? wrwi.x : (mat ? wrwi.y : -wrwi.y);
      }
      __half2 hh = __floats2half2_rn(v[0], v[1]);
      wbits[jj] = *(uint*)&hh;
    }
    Bfrag[tt] = make_uint4(wbits[0], wbits[1], wbits[2], wbits[3]);
  }
}

// ---------- fused sparse gather + MFMA epilogue ----------
// One wave per 16-node tile (tiles from a global atomic counter).
// Gather per node: lane l handles features 4*(l&15)..+3 of edge j+(l>>4); one
// dwordx4 gather covers 4 edges per wave-instruction; idx entry carries the
// f16 inv scale in bits [17,32). After the shfl reduce, lanes 0..15 stage the
// node's 192-f16 row [p|sh|u] into a per-wave LDS tile, XOR-swizzled in 16 B
// units (unit ^= node&7) so epilogue ds_read_b128 is low-conflict.
// Epilogue per tile: 6 swizzled ds_read_b128 A-frags + 32 mfma_f32_16x16x32_f16
// with B-frags from global (L2-resident 32 KB).
//   real: C = sum_kt A(kt)*Br(kt), k in [0,128);  imag: A(kt+2)*Bi(kt), [64,192)
// A-frag: row = lane&15, k = 8*(lane>>4)+j. C/D: col = lane&15, row = 4*(lane>>4)+reg.
__global__ __launch_bounds__(256, 6) void gather_kernel(
    const uint4* __restrict__ xp4,
    const uint* __restrict__ idx_out, const uint* __restrict__ idx_in,
    const int* __restrict__ ofs_out, const int* __restrict__ ofs_in,
    const float* __restrict__ inv_out, const float* __restrict__ inv_in,
    const uint4* __restrict__ Bfrag, const float* __restrict__ cR,
    const float* __restrict__ cI, int* __restrict__ tile_ctr,
    float* __restrict__ out_real, float* __restrict__ out_imag, int N) {
  __shared__ uint sA[4][1536];  // per wave: 16 nodes x 96 dwords (192 f16), swizzled
  int wv = threadIdx.x >> 6;
  int lane = threadIdx.x & 63;
  int sub = lane >> 4;  // edge slot 0..3
  int q = lane & 15;    // uint4 slot -> features 4q..4q+3
  uint* myA = sA[wv];
  float bR[4], bI[4];
#pragma unroll
  for (int nt = 0; nt < 4; ++nt) {
    bR[nt] = cR[q + 16 * nt];
    bI[nt] = cI[q + 16 * nt];
  }
  int tiles = N >> 4;  // 6250 (N multiple of 16)
  for (;;) {
    int tt;
    if (lane == 0) tt = atomicAdd(tile_ctr, 1);
    tt = __shfl(tt, 0);
    if (tt >= tiles) break;
    int n0 = tt << 4;
    for (int i = 0; i < 16; ++i) {
      int n = n0 + i;
      float4 u1 = {0, 0, 0, 0}, s1 = {0, 0, 0, 0};
      float4 v2 = {0, 0, 0, 0}, s2 = {0, 0, 0, 0};
#define ACC(P, SC, U, S)                                                \
  {                                                                     \
    float2 a0 = h2_to_f2((P).x), a1 = h2_to_f2((P).y);                  \
    float2 a2 = h2_to_f2((P).z), a3 = h2_to_f2((P).w);                  \
    U.x += SC * a0.x; S.x += SC * a0.y; U.y += SC * a1.x; S.y += SC * a1.y; \
    U.z += SC * a2.x; S.z += SC * a2.y; U.w += SC * a3.x; S.w += SC * a3.y; \
  }
#define DEC(E) __half2float(__ushort_as_half((ushort)((E) >> 17)))
      {  // out-direction: neighbors scaled by inv_in[nbr] (in idx bits)
        int lo = ofs_out[n], hi = ofs_out[n + 1];
        int len8 = (hi - lo) & ~7;
        int j = lo;
        for (; j < lo + len8; j += 8) {
          uint e0 = idx_out[j + sub];
          uint e1 = idx_out[j + 4 + sub];
          uint4 p0 = xp4[(size_t)(e0 & 0x1FFFFu) * 16 + q];
          uint4 p1 = xp4[(size_t)(e1 & 0x1FFFFu) * 16 + q];
          float sc0 = DEC(e0), sc1 = DEC(e1);
          ACC(p0, sc0, u1, s1);
          ACC(p1, sc1, u1, s1);
        }
        for (; j < hi; j += 4) {
          if (j + sub < hi) {
            uint e0 = idx_out[j + sub];
            uint4 p0 = xp4[(size_t)(e0 & 0x1FFFFu) * 16 + q];
            float sc0 = DEC(e0);
            ACC(p0, sc0, u1, s1);
          }
        }
      }
      {  // in-direction: neighbors scaled by inv_out[nbr] (in idx bits)
        int lo = ofs_in[n], hi = ofs_in[n + 1];
        int len8 = (hi - lo) & ~7;
        int j = lo;
        for (; j < lo + len8; j += 8) {
          uint e0 = idx_in[j + sub];
          uint e1 = idx_in[j + 4 + sub];
          uint4 p0 = xp4[(size_t)(e0 & 0x1FFFFu) * 16 + q];
          uint4 p1 = xp4[(size_t)(e1 & 0x1FFFFu) * 16 + q];
          float sc0 = DEC(e0), sc1 = DEC(e1);
          ACC(p0, sc0, v2, s2);
          ACC(p1, sc1, v2, s2);
        }
        for (; j < hi; j += 4) {
          if (j + sub < hi) {
            uint e0 = idx_in[j + sub];
            uint4 p0 = xp4[(size_t)(e0 & 0x1FFFFu) * 16 + q];
            float sc0 = DEC(e0);
            ACC(p0, sc0, v2, s2);
          }
        }
      }
#undef ACC
#undef DEC
      // reduce the 4 edge-subgroups (lanes l, l^16, l^32, l^48)
#pragma unroll
      for (int m = 16; m < 64; m <<= 1) {
        u1.x += __shfl_xor(u1.x, m); u1.y += __shfl_xor(u1.y, m);
        u1.z += __shfl_xor(u1.z, m); u1.w += __shfl_xor(u1.w, m);
        s1.x += __shfl_xor(s1.x, m); s1.y += __shfl_xor(s1.y, m);
        s1.z += __shfl_xor(s1.z, m); s1.w += __shfl_xor(s1.w, m);
        v2.x += __shfl_xor(v2.x, m); v2.y += __shfl_xor(v2.y, m);
        v2.z += __shfl_xor(v2.z, m); v2.w += __shfl_xor(v2.w, m);
        s2.x += __shfl_xor(s2.x, m); s2.y += __shfl_xor(s2.y, m);
        s2.z += __shfl_xor(s2.z, m); s2.w += __shfl_xor(s2.w, m);
      }
      if (sub == 0) {  // lanes 0..15 hold features 4q..4q+3 -> stage to LDS
        float io = inv_out[n], ii = inv_in[n];
        float4 uu = make_float4(io * u1.x, io * u1.y, io * u1.z, io * u1.w);
        float4 vv = make_float4(ii * v2.x, ii * v2.y, ii * v2.z, ii * v2.w);
        float4 ss = make_float4(io * s1.x + ii * s2.x, io * s1.y + ii * s2.y,
                                io * s1.z + ii * s2.z, io * s1.w + ii * s2.w);
        int u0 = q >> 1, kk = i & 7;
        uint base = (uint)(i * 96 + ((q & 1) << 1));
        __half2 h;
        uint2 w;
        h = __floats2half2_rn(0.5f * (uu.x + vv.x), 0.5f * (uu.y + vv.y)); w.x = *(uint*)&h;
        h = __floats2half2_rn(0.5f * (uu.z + vv.z), 0.5f * (uu.w + vv.w)); w.y = *(uint*)&h;
        *(uint2*)&myA[base + 4 * (u0 ^ kk)] = w;           // p  (units 0..7)
        h = __floats2half2_rn(0.5f * ss.x, 0.5f * ss.y); w.x = *(uint*)&h;
        h = __floats2half2_rn(0.5f * ss.z, 0.5f * ss.w); w.y = *(uint*)&h;
        *(uint2*)&myA[base + 4 * ((8 + u0) ^ kk)] = w;     // sh (units 8..15)
        h = __floats2half2_rn(uu.x, uu.y); w.x = *(uint*)&h;
        h = __floats2half2_rn(uu.z, uu.w); w.y = *(uint*)&h;
        *(uint2*)&myA[base + 4 * ((16 + u0) ^ kk)] = w;    // u  (units 16..23)
      }
    }
    // ---- MFMA epilogue (wave-synchronous LDS RAW; same-wave DS ops ordered) ----
    int l15 = q, l4 = sub, rk = l15 & 7;
    f16x8 a[6];
#pragma unroll
    for (int sct = 0; sct < 6; ++sct) {
      int slot = ((sct >> 1) << 3) + ((((sct & 1) << 2) + l4) ^ rk);
      a[sct] = *(const f16x8*)&myA[l15 * 96 + 4 * slot];
    }
    f32x4 cr[4], ci[4];
#pragma unroll
    for (int nt = 0; nt < 4; ++nt) {
      cr[nt] = (f32x4){0.f, 0.f, 0.f, 0.f};
      ci[nt] = (f32x4){0.f, 0.f, 0.f, 0.f};
    }
#pragma unroll
    for (int kt = 0; kt < 4; ++kt) {
#pragma unroll
      for (int nt = 0; nt < 4; ++nt) {
        f16x8 b0 = *(const f16x8*)&Bfrag[(kt * 4 + nt) * 64 + lane];
        cr[nt] = __builtin_amdgcn_mfma_f32_16x16x32_f16(a[kt], b0, cr[nt], 0, 0, 0);
        f16x8 b1 = *(const f16x8*)&Bfrag[(16 + kt * 4 + nt) * 64 + lane];
        ci[nt] = __builtin_amdgcn_mfma_f32_16x16x32_f16(a[kt + 2], b1, ci[nt], 0, 0, 0);
      }
    }
#pragma unroll
    for (int nt = 0; nt < 4; ++nt) {
#pragma unroll
      for (int r = 0; r < 4; ++r) {
        size_t node = (size_t)(n0 + 4 * l4 + r);
        out_real[node * 64 + l15 + 16 * nt] = cr[nt][r] + bR[nt];
        out_imag[node * 64 + l15 + 16 * nt] = ci[nt][r] + bI[nt];
      }
    }
  }
}

extern "C" void kernel_launch(void* const* d_in, const int* in_sizes, int n_in,
                              void* d_out, int out_size, void* d_ws, size_t ws_size,
                              hipStream_t stream) {
  const float* x_real = (const float*)d_in[0];
  const float* x_imag = (const float*)d_in[1];
  const int* edge = (const int*)d_in[2];
  const float* W_real = (const float*)d_in[3];
  const float* b_real = (const float*)d_in[4];
  const float* W_imag = (const float*)d_in[5];
  const float* b_imag = (const float*)d_in[6];

  const int N = in_sizes[0] / D;  // 100000
  const int E = in_sizes[2] / 2;  // 1600000
  const int* row = edge;
  const int* col = edge + E;

  const int NBUK = (N + 511) >> 9;          // 196 buckets of 512 nodes
  const int CH = (E + G1 - 1) / G1;         // edges per partition block
  const int L = NBUK * G1;                  // flattened histogram length
  const int GB = (L + SB - 1) / SB;         // scan blocks for histograms
  const int NB = (N + SB - 1) / SB;         // scan blocks for degrees

  // workspace layout (16B-aligned packed arrays first)
  uint* xp       = (uint*)d_ws;                    // N*64 (unscaled half2 pack)
  uint* idx_out  = xp + (size_t)N * D;             // E
  uint* idx_in   = idx_out + E;                    // E
  uint* pout     = idx_in + E;                     // E (bucketed packs)
  uint* pin      = pout + E;                       // E
  uint4* Bfrag   = (uint4*)(pin + E);              // 2048 uint4 = 32 KB
  int* hout      = (int*)(Bfrag + 2048);           // L
  int* hin       = hout + L;                       // L
  int* gbs       = hin + L;                        // 2*GB
  int* deg_out   = gbs + 2 * GB;                   // N
  int* deg_in    = deg_out + N;                    // N
  int* ofs_out   = deg_in + N;                     // N+1
  int* ofs_in    = ofs_out + N + 1;                // N+1
  float* inv_out = (float*)(ofs_in + N + 1);       // N
  float* inv_in  = inv_out + N;                    // N
  float* cR      = inv_in + N;                     // 64
  float* cI      = cR + 64;                        // 64
  int* bsum      = (int*)(cI + 64);                // 2*NB
  int* tile_ctr  = bsum + 2 * NB;                  // 1

  float* out_real = (float*)d_out;
  float* out_imag = out_real + (size_t)N * D;

  wprep_kernel<<<1, 1024, 0, stream>>>(W_real, b_real, W_imag, b_imag,
                                       Bfrag, cR, cI, tile_ctr);

  // unscaled feature pack (no dependency on the degree chain)
  pack_kernel<<<(N * 16 + 255) / 256, 256, 0, stream>>>(x_real, x_imag, xp, N * 16);

  // bucket partition of edges (both directions)
  part_count<<<G1, 256, 0, stream>>>(row, col, hout, hin, E, NBUK, CH);
  bsum_kernel<<<dim3(GB, 2), SB, 0, stream>>>(hout, hin, gbs, L, GB);
  bscan_kernel<<<1, 1024, 0, stream>>>(gbs, GB);
  gfin_kernel<<<dim3(GB, 2), SB, 0, stream>>>(hout, hin, gbs, L, GB);
  part_scatter<<<G1, 256, 0, stream>>>(row, col, hout, hin, pout, pin, E, NBUK, CH);

  // per-bucket degrees -> exclusive ofs + inv
  bucket_degree<<<dim3(NBUK, 2), 256, 0, stream>>>(pout, pin, hout, hin,
                                                   deg_out, deg_in, E, NBUK, N);
  bsum_kernel<<<dim3(NB, 2), SB, 0, stream>>>(deg_out, deg_in, bsum, N, NB);
  bscan_kernel<<<1, 1024, 0, stream>>>(bsum, NB);
  sfin_kernel<<<dim3(NB, 2), SB, 0, stream>>>(deg_out, deg_in, bsum, ofs_out, ofs_in,
                                              inv_out, inv_in, N, NB);

  // per-bucket CSR fill (block-private windows; packs inv scale into idx)
  bucket_fill<<<dim3(NBUK, 2), 256, 0, stream>>>(pout, pin, hout, hin, ofs_out, ofs_in,
                                                 inv_out, inv_in, idx_out, idx_in,
                                                 E, NBUK, N);
  // fused sparse gather + MFMA epilogue (dynamic tile counter)
  gather_kernel<<<1568, 256, 0, stream>>>((const uint4*)xp, idx_out, idx_in,
                                          ofs_out, ofs_in, inv_out, inv_in,
                                          Bfrag, cR, cI, tile_ctr,
                                          out_real, out_imag, N);
}

// Round 4
// 344.149 us; speedup vs baseline: 1.5565x; 1.5565x over previous
//
#include <hip/hip_runtime.h>
#include <hip/hip_fp16.h>

// ComplexFaberConv: degree-normalized directed SpMM + collapsed complex linear.
//
// Math (linear in k, so W-stacks collapse):
//   WrE = sum_k 0.5^k W_real[k], WiE likewise; brE, biE likewise.
//   u = y_real, v = y_real_t, S = y_imag + y_imag_t
//   total_real = 0.5*(u+v)@WrE^T - 0.5*S@WiE^T + (brE-biE)
//   total_imag = u@WiE^T + 0.5*S@WrE^T + (brE+biE)
// (reference faithfully uses y_real, not y_real_t, in sum_imag_d2s)
//
// R7: MFMA gemm epilogue in its own dispatch (gather 211 -> 124 us).
// R8: single unscaled xp array, per-edge inv scale packed in idx bits
//     (gather 124 -> 113 us; L2-churn-limited, structural).
// R9 FAILED: fusing gemm into gather tanked occupancy/MLP (113 -> 324 us).
//     Reverted: gather and gemm restored to R8 form verbatim.
// R10 (this round): CSR-build chain restructured 14 -> 9 dispatches:
//   - part_count emits per-bucket TOTALS only (196x2 atomics) — the L=50K
//     histogram + its 3-dispatch scan are gone.
//   - part_scatter self-reserves ranges via atomic bucket cursors (order
//     within a bucket never mattered).
//   - bucket bases: 196-entry scan folded into prep_kernel (with weights).
//   - offsets_kernel: per-bucket LDS degree histogram + LOCAL 512-scan ->
//     ofs/inv directly (ofs = bucket_base + local_prefix) — replaces
//     bucket_degree + the N-length 3-dispatch scan chain.

constexpr int D = 64;
constexpr int G1 = 256;   // partition blocks

typedef _Float16 f16x8 __attribute__((ext_vector_type(8)));
typedef float f32x4 __attribute__((ext_vector_type(4)));

__device__ __forceinline__ float2 h2_to_f2(uint p) {
  __half2 h = *(__half2*)&p;
  return __half22float2(h);
}

// ---------- partition phase ----------

// Per-block LDS bucket histogram -> global per-bucket totals (atomics).
// bucket = node>>9. Tcnt[0..NBUK) = out-dir, Tcnt[NBUK..2*NBUK) = in-dir.
__global__ __launch_bounds__(256) void part_count(
    const int* __restrict__ row, const int* __restrict__ col,
    int* __restrict__ Tcnt, int E, int NBUK, int CH) {
  __shared__ int ho[256], hi_[256];
  int t = threadIdx.x, g = blockIdx.x;
  ho[t] = 0;
  hi_[t] = 0;
  __syncthreads();
  int e0 = g * CH, e1 = min(E, e0 + CH);
  for (int e = e0 + t; e < e1; e += 256) {
    atomicAdd(&ho[row[e] >> 9], 1);
    atomicAdd(&hi_[col[e] >> 9], 1);
  }
  __syncthreads();
  if (t < NBUK) {
    if (ho[t]) atomicAdd(&Tcnt[t], ho[t]);
    if (hi_[t]) atomicAdd(&Tcnt[NBUK + t], hi_[t]);
  }
}

// Fused prep: (a) 196-entry exclusive scan of bucket totals -> bases Bb_* and
// atomic cursors Ccur; (b) collapse K=3 weight stacks (LDS Wh) and emit MFMA
// B-fragments + collapsed biases.
//   Bfrag[fr][lane] = 8 f16, fr = ((mat*4+kt)*4+nt), element:
//     k_local = 8*(lane>>4) + j + 32*kt  (0..127),  o = (lane&15) + 16*nt
//     mat 0 (real): k<64 -> wr[k][o], else -wi[k-64][o]
//     mat 1 (imag): k<64 -> wr[k][o], else +wi[k-64][o]
__global__ __launch_bounds__(1024) void prep_kernel(
    const float* __restrict__ Wr, const float* __restrict__ br,
    const float* __restrict__ Wi, const float* __restrict__ bi,
    const int* __restrict__ Tcnt, uint4* __restrict__ Bfrag,
    float* __restrict__ cR, float* __restrict__ cI,
    int* __restrict__ Bb_out, int* __restrict__ Bb_in, int* __restrict__ Ccur,
    int E, int NBUK) {
  __shared__ uint sWh[4096];  // Wh[d*64+o]
  __shared__ int ws[8];
  int t = threadIdx.x;
  for (int i = t; i < 4096; i += 1024) {
    int o = i >> 6, d = i & 63;
    float wr = Wr[i] + 0.5f * Wr[4096 + i] + 0.25f * Wr[8192 + i];
    float wi = Wi[i] + 0.5f * Wi[4096 + i] + 0.25f * Wi[8192 + i];
    __half2 h = __floats2half2_rn(wr, wi);
    sWh[d * 64 + o] = *(uint*)&h;
  }
  if (t < 64) {
    float brv = br[t] + 0.5f * br[64 + t] + 0.25f * br[128 + t];
    float biv = bi[t] + 0.5f * bi[64 + t] + 0.25f * bi[128 + t];
    cR[t] = brv - biv;
    cI[t] = brv + biv;
  }
  // scan of bucket totals: threads 0..511, dir = t>>8 (waves 0..3 / 4..7)
  int dir = 0, tl = 0, v = 0, sc = 0;
  int lane = t & 63, wv = t >> 6;
  if (t < 512) {
    dir = t >> 8;
    tl = t & 255;
    v = (tl < NBUK) ? Tcnt[dir * NBUK + tl] : 0;
    sc = v;
#pragma unroll
    for (int off = 1; off < 64; off <<= 1) {
      int u = __shfl_up(sc, off);
      if (lane >= off) sc += u;
    }
    if (lane == 63) ws[wv] = sc;
  }
  __syncthreads();
  if (t < 512) {
    int wbase = 0;
#pragma unroll
    for (int w = 0; w < 8; ++w)
      if (w >= (dir << 2) && w < wv) wbase += ws[w];
    int excl = wbase + sc - v;
    int* Bb = dir ? Bb_in : Bb_out;
    if (tl < NBUK) {
      Bb[tl] = excl;
      Ccur[dir * NBUK + tl] = excl;
      if (tl == NBUK - 1) Bb[NBUK] = excl + v;  // == E
    }
  }
  // B-fragment emit (sWh ready after the sync above)
  for (int tt = t; tt < 2048; tt += 1024) {
    int ln = tt & 63, fr = tt >> 6;
    int mat = fr >> 4, kt = (fr >> 2) & 3, nt = fr & 3;
    int o = (ln & 15) + 16 * nt;
    int k0 = 8 * (ln >> 4) + 32 * kt;
    uint wbits[4];
#pragma unroll
    for (int jj = 0; jj < 4; ++jj) {
      float vv[2];
#pragma unroll
      for (int s = 0; s < 2; ++s) {
        int k = k0 + 2 * jj + s;
        float2 wrwi = h2_to_f2(sWh[(k & 63) * 64 + o]);
        vv[s] = (k < 64) ? wrwi.x : (mat ? wrwi.y : -wrwi.y);
      }
      __half2 hh = __floats2half2_rn(vv[0], vv[1]);
      wbits[jj] = *(uint*)&hh;
    }
    Bfrag[tt] = make_uint4(wbits[0], wbits[1], wbits[2], wbits[3]);
  }
}

// Scatter edges into bucket-contiguous regions. Each block counts its chunk
// (LDS histogram), reserves a range per bucket via ONE global atomicAdd on the
// bucket cursor, then scatters through LDS cursors. Order within a bucket is
// arbitrary (irrelevant downstream).
// pack = (node_local<<17) | neighbor  (node_local<512 -> 9b, neighbor -> 17b)
__global__ __launch_bounds__(256) void part_scatter(
    const int* __restrict__ row, const int* __restrict__ col,
    int* __restrict__ Ccur,
    uint* __restrict__ pout, uint* __restrict__ pin, int E, int NBUK, int CH) {
  __shared__ int co[256], ci[256];
  int t = threadIdx.x, g = blockIdx.x;
  co[t] = 0;
  ci[t] = 0;
  __syncthreads();
  int e0 = g * CH, e1 = min(E, e0 + CH);
  for (int e = e0 + t; e < e1; e += 256) {
    atomicAdd(&co[row[e] >> 9], 1);
    atomicAdd(&ci[col[e] >> 9], 1);
  }
  __syncthreads();
  if (t < NBUK) {
    int c = co[t];
    co[t] = c ? atomicAdd(&Ccur[t], c) : 0;
    c = ci[t];
    ci[t] = c ? atomicAdd(&Ccur[NBUK + t], c) : 0;
  }
  __syncthreads();
  for (int e = e0 + t; e < e1; e += 256) {
    int r = row[e], c = col[e];
    int po = atomicAdd(&co[r >> 9], 1);
    pout[po] = ((uint)(r & 511) << 17) | (uint)c;
    int pi = atomicAdd(&ci[c >> 9], 1);
    pin[pi] = ((uint)(c & 511) << 17) | (uint)r;
  }
}

// One block per bucket: LDS degree histogram + LOCAL 512-element exclusive scan
// -> ofs (= bucket_base + local_prefix; buckets are node-contiguous) and
// inv = deg^-0.25. Replaces the global N-length scan chain.
__global__ __launch_bounds__(256) void offsets_kernel(
    const uint* __restrict__ pout, const uint* __restrict__ pin,
    const int* __restrict__ Bb_out, const int* __restrict__ Bb_in,
    int* __restrict__ ofs_out, int* __restrict__ ofs_in,
    float* __restrict__ inv_out, float* __restrict__ inv_in,
    int E, int NBUK, int N) {
  const uint* p = blockIdx.y ? pin : pout;
  const int* Bb = blockIdx.y ? Bb_in : Bb_out;
  int* ofs = blockIdx.y ? ofs_in : ofs_out;
  float* inv = blockIdx.y ? inv_in : inv_out;
  __shared__ int ld[512];
  __shared__ int ws[4];
  int t = threadIdx.x, b = blockIdx.x;
  ld[t] = 0;
  ld[t + 256] = 0;
  __syncthreads();
  int win_s = Bb[b], win_e = Bb[b + 1];
  for (int j = win_s + t; j < win_e; j += 256) atomicAdd(&ld[p[j] >> 17], 1);
  __syncthreads();
  int a0 = ld[2 * t], a1 = ld[2 * t + 1], sm = a0 + a1;
  int lane = t & 63, wv = t >> 6, sc = sm;
#pragma unroll
  for (int off = 1; off < 64; off <<= 1) {
    int u = __shfl_up(sc, off);
    if (lane >= off) sc += u;
  }
  if (lane == 63) ws[wv] = sc;
  __syncthreads();
  int wbase = 0;
#pragma unroll
  for (int w = 0; w < 4; ++w)
    if (w < wv) wbase += ws[w];
  int excl = wbase + sc - sm;
  int n0 = (b << 9) + 2 * t;
  if (n0 < N) {
    ofs[n0] = win_s + excl;
    inv[n0] = a0 ? rsqrtf(sqrtf((float)a0)) : 0.0f;
  }
  if (n0 + 1 < N) {
    ofs[n0 + 1] = win_s + excl + a0;
    inv[n0 + 1] = a1 ? rsqrtf(sqrtf((float)a1)) : 0.0f;
  }
  if (b == 0 && t == 0) ofs[N] = E;
}

// One block per bucket: LDS cursors seeded from ofs; idx window is block-private.
// idx entry = (f16bits(inv_of_neighbor)<<17) | neighbor. y=0: pout->idx_out,
// neighbors are cols -> inv_in; y=1: pin->idx_in, neighbors are rows -> inv_out.
__global__ __launch_bounds__(256) void bucket_fill(
    const uint* __restrict__ pout, const uint* __restrict__ pin,
    const int* __restrict__ Bb_out, const int* __restrict__ Bb_in,
    const int* __restrict__ ofs_out, const int* __restrict__ ofs_in,
    const float* __restrict__ inv_out, const float* __restrict__ inv_in,
    uint* __restrict__ idx_out, uint* __restrict__ idx_in, int E, int NBUK, int N) {
  const uint* p = blockIdx.y ? pin : pout;
  const int* Bb = blockIdx.y ? Bb_in : Bb_out;
  const int* ofs = blockIdx.y ? ofs_in : ofs_out;
  const float* invnb = blockIdx.y ? inv_out : inv_in;
  uint* idx = blockIdx.y ? idx_in : idx_out;
  __shared__ int cur[512];
  int t = threadIdx.x, b = blockIdx.x;
  int n0 = (b << 9) + t;
  cur[t] = (n0 < N) ? ofs[n0] : 0;
  cur[t + 256] = (n0 + 256 < N) ? ofs[n0 + 256] : 0;
  __syncthreads();
  int s = Bb[b], e = Bb[b + 1];
  for (int j = s + t; j < e; j += 256) {
    uint pk = p[j];
    uint nbr = pk & 0x1FFFFu;
    uint hb = (uint)__half_as_ushort(__float2half(invnb[nbr]));  // <= 0x3C00
    int pos = atomicAdd(&cur[pk >> 17], 1);
    idx[pos] = (hb << 17) | nbr;
  }
}

// ---------- dense prep ----------

// Unscaled packed features: xp[n*64+d] = half2(xr, xi). 25.6 MB, single array
// for both gather directions (scale rides in the idx entries).
__global__ void pack_kernel(const float* __restrict__ xr, const float* __restrict__ xi,
                            uint* __restrict__ xp, int total4) {
  int i = blockIdx.x * blockDim.x + threadIdx.x;  // over N*16 uint4 groups
  if (i < total4) {
    float4 a = ((const float4*)xr)[i];
    float4 b = ((const float4*)xi)[i];
    __half2 h;
    uint4 o;
    h = __floats2half2_rn(a.x, b.x); o.x = *(uint*)&h;
    h = __floats2half2_rn(a.y, b.y); o.y = *(uint*)&h;
    h = __floats2half2_rn(a.z, b.z); o.z = *(uint*)&h;
    h = __floats2half2_rn(a.w, b.w); o.w = *(uint*)&h;
    ((uint4*)xp)[i] = o;
  }
}

// ---------- sparse gather (R8 form, verbatim) ----------
// One wave per node. Lane l handles features 4*(l&15)..+3 of edge j+(l>>4):
// one dwordx4 gather covers 4 edges per wave-instruction; unroll 2.
// idx entry = (f16bits(inv_nbr)<<17)|nbr; accumulate via fma with decoded scale.
// Output: Apack[n][k], k in [0,192) f16: [p(64) | sh(64) | u(64)], written by
// the sub==0 quarter-wave. No LDS (epilogue lives in gemm_kernel).
__global__ __launch_bounds__(256) void gather_kernel(
    const uint4* __restrict__ xp4,
    const uint* __restrict__ idx_out, const uint* __restrict__ idx_in,
    const int* __restrict__ ofs_out, const int* __restrict__ ofs_in,
    const float* __restrict__ inv_out, const float* __restrict__ inv_in,
    uint* __restrict__ Apack, int N) {
  int wv = threadIdx.x >> 6;
  int lane = threadIdx.x & 63;
  int sub = lane >> 4;  // edge slot 0..3
  int q = lane & 15;    // uint4 slot -> features 4q..4q+3
  int wid = blockIdx.x * 4 + wv;
  int nw = gridDim.x * 4;
  for (int n = wid; n < N; n += nw) {
    float4 u1 = {0, 0, 0, 0}, s1 = {0, 0, 0, 0};
    float4 v2 = {0, 0, 0, 0}, s2 = {0, 0, 0, 0};
#define ACC(P, SC, U, S)                                                \
  {                                                                     \
    float2 a0 = h2_to_f2((P).x), a1 = h2_to_f2((P).y);                  \
    float2 a2 = h2_to_f2((P).z), a3 = h2_to_f2((P).w);                  \
    U.x += SC * a0.x; S.x += SC * a0.y; U.y += SC * a1.x; S.y += SC * a1.y; \
    U.z += SC * a2.x; S.z += SC * a2.y; U.w += SC * a3.x; S.w += SC * a3.y; \
  }
#define DEC(E) __half2float(__ushort_as_half((ushort)((E) >> 17)))
    {  // out-direction: neighbors scaled by inv_in[nbr] (in idx bits)
      int lo = ofs_out[n], hi = ofs_out[n + 1];
      int len8 = (hi - lo) & ~7;
      int j = lo;
      for (; j < lo + len8; j += 8) {
        uint e0 = idx_out[j + sub];
        uint e1 = idx_out[j + 4 + sub];
        uint4 p0 = xp4[(size_t)(e0 & 0x1FFFFu) * 16 + q];
        uint4 p1 = xp4[(size_t)(e1 & 0x1FFFFu) * 16 + q];
        float sc0 = DEC(e0), sc1 = DEC(e1);
        ACC(p0, sc0, u1, s1);
        ACC(p1, sc1, u1, s1);
      }
      for (; j < hi; j += 4) {
        if (j + sub < hi) {
          uint e0 = idx_out[j + sub];
          uint4 p0 = xp4[(size_t)(e0 & 0x1FFFFu) * 16 + q];
          float sc0 = DEC(e0);
          ACC(p0, sc0, u1, s1);
        }
      }
    }
    {  // in-direction: neighbors scaled by inv_out[nbr] (in idx bits)
      int lo = ofs_in[n], hi = ofs_in[n + 1];
      int len8 = (hi - lo) & ~7;
      int j = lo;
      for (; j < lo + len8; j += 8) {
        uint e0 = idx_in[j + sub];
        uint e1 = idx_in[j + 4 + sub];
        uint4 p0 = xp4[(size_t)(e0 & 0x1FFFFu) * 16 + q];
        uint4 p1 = xp4[(size_t)(e1 & 0x1FFFFu) * 16 + q];
        float sc0 = DEC(e0), sc1 = DEC(e1);
        ACC(p0, sc0, v2, s2);
        ACC(p1, sc1, v2, s2);
      }
      for (; j < hi; j += 4) {
        if (j + sub < hi) {
          uint e0 = idx_in[j + sub];
          uint4 p0 = xp4[(size_t)(e0 & 0x1FFFFu) * 16 + q];
          float sc0 = DEC(e0);
          ACC(p0, sc0, v2, s2);
        }
      }
    }
#undef ACC
#undef DEC
    // reduce the 4 edge-subgroups (lanes l, l^16, l^32, l^48)
#pragma unroll
    for (int m = 16; m < 64; m <<= 1) {
      u1.x += __shfl_xor(u1.x, m); u1.y += __shfl_xor(u1.y, m);
      u1.z += __shfl_xor(u1.z, m); u1.w += __shfl_xor(u1.w, m);
      s1.x += __shfl_xor(s1.x, m); s1.y += __shfl_xor(s1.y, m);
      s1.z += __shfl_xor(s1.z, m); s1.w += __shfl_xor(s1.w, m);
      v2.x += __shfl_xor(v2.x, m); v2.y += __shfl_xor(v2.y, m);
      v2.z += __shfl_xor(v2.z, m); v2.w += __shfl_xor(v2.w, m);
      s2.x += __shfl_xor(s2.x, m); s2.y += __shfl_xor(s2.y, m);
      s2.z += __shfl_xor(s2.z, m); s2.w += __shfl_xor(s2.w, m);
    }
    if (sub == 0) {  // lanes 0..15 hold features 4q..4q+3
      float io = inv_out[n], ii = inv_in[n];
      float4 uu = make_float4(io * u1.x, io * u1.y, io * u1.z, io * u1.w);
      float4 vv = make_float4(ii * v2.x, ii * v2.y, ii * v2.z, ii * v2.w);
      float4 ss = make_float4(io * s1.x + ii * s2.x, io * s1.y + ii * s2.y,
                              io * s1.z + ii * s2.z, io * s1.w + ii * s2.w);
      uint* base = Apack + (size_t)n * 96 + 2 * q;  // row = 192 f16 = 96 uints
      __half2 h;
      uint2 w;
      h = __floats2half2_rn(0.5f * (uu.x + vv.x), 0.5f * (uu.y + vv.y)); w.x = *(uint*)&h;
      h = __floats2half2_rn(0.5f * (uu.z + vv.z), 0.5f * (uu.w + vv.w)); w.y = *(uint*)&h;
      *(uint2*)base = w;  // p
      h = __floats2half2_rn(0.5f * ss.x, 0.5f * ss.y); w.x = *(uint*)&h;
      h = __floats2half2_rn(0.5f * ss.z, 0.5f * ss.w); w.y = *(uint*)&h;
      *(uint2*)(base + 32) = w;  // sh
      h = __floats2half2_rn(uu.x, uu.y); w.x = *(uint*)&h;
      h = __floats2half2_rn(uu.z, uu.w); w.y = *(uint*)&h;
      *(uint2*)(base + 64) = w;  // u
    }
  }
}

// ---------- dense epilogue: tall-skinny MFMA GEMM (R8 form, verbatim) ----------
// Per wave per 16-node tile: 6 A-frags (k windows of 32), 32 mfma_f32_16x16x32_f16.
//   real: C[n][o]   = sum_{kt=0..3} A(kt)   * Breal(kt)   (k in [0,128))
//   imag: C[n][o]   = sum_{kt=0..3} A(kt+2) * Bimag(kt)   (k in [64,192))
// A-frag: row = lane&15, k = 8*(lane>>4)+j. B-frag: col = lane&15, same k.
// C/D: col = lane&15, row = 4*(lane>>4)+reg  [m89-verified layout].
__global__ __launch_bounds__(256) void gemm_kernel(
    const ushort* __restrict__ Apack, const uint4* __restrict__ Bfrag,
    const float* __restrict__ cR, const float* __restrict__ cI,
    float* __restrict__ out_real, float* __restrict__ out_imag, int N) {
  __shared__ uint4 sB[2048];  // 32 KB: [fr(32)][lane(64)]
  for (int i = threadIdx.x; i < 2048; i += 256) sB[i] = Bfrag[i];
  __syncthreads();
  int lane = threadIdx.x & 63, wv = threadIdx.x >> 6;
  int l15 = lane & 15, l4 = lane >> 4;
  float bR[4], bI[4];
#pragma unroll
  for (int nt = 0; nt < 4; ++nt) {
    bR[nt] = cR[l15 + 16 * nt];
    bI[nt] = cI[l15 + 16 * nt];
  }
  int tiles = (N + 15) >> 4;
  int gw = blockIdx.x * 4 + wv, nw = gridDim.x * 4;
  for (int tt = gw; tt < tiles; tt += nw) {
    int n0 = tt << 4;
    int arow = min(n0 + l15, N - 1);
    const ushort* ap = Apack + (size_t)arow * 192 + 8 * l4;
    f16x8 a[6];
#pragma unroll
    for (int kt = 0; kt < 6; ++kt) a[kt] = *(const f16x8*)(ap + 32 * kt);
    f32x4 cr[4], ci[4];
#pragma unroll
    for (int nt = 0; nt < 4; ++nt) {
      cr[nt] = (f32x4){0.f, 0.f, 0.f, 0.f};
      ci[nt] = (f32x4){0.f, 0.f, 0.f, 0.f};
    }
#pragma unroll
    for (int kt = 0; kt < 4; ++kt) {
#pragma unroll
      for (int nt = 0; nt < 4; ++nt) {
        f16x8 b0 = *(const f16x8*)&sB[(kt * 4 + nt) * 64 + lane];
        cr[nt] = __builtin_amdgcn_mfma_f32_16x16x32_f16(a[kt], b0, cr[nt], 0, 0, 0);
        f16x8 b1 = *(const f16x8*)&sB[(16 + kt * 4 + nt) * 64 + lane];
        ci[nt] = __builtin_amdgcn_mfma_f32_16x16x32_f16(a[kt + 2], b1, ci[nt], 0, 0, 0);
      }
    }
#pragma unroll
    for (int nt = 0; nt < 4; ++nt) {
#pragma unroll
      for (int r = 0; r < 4; ++r) {
        int node = n0 + 4 * l4 + r;
        if (node < N) {
          out_real[(size_t)node * 64 + l15 + 16 * nt] = cr[nt][r] + bR[nt];
          out_imag[(size_t)node * 64 + l15 + 16 * nt] = ci[nt][r] + bI[nt];
        }
      }
    }
  }
}

extern "C" void kernel_launch(void* const* d_in, const int* in_sizes, int n_in,
                              void* d_out, int out_size, void* d_ws, size_t ws_size,
                              hipStream_t stream) {
  const float* x_real = (const float*)d_in[0];
  const float* x_imag = (const float*)d_in[1];
  const int* edge = (const int*)d_in[2];
  const float* W_real = (const float*)d_in[3];
  const float* b_real = (const float*)d_in[4];
  const float* W_imag = (const float*)d_in[5];
  const float* b_imag = (const float*)d_in[6];

  const int N = in_sizes[0] / D;  // 100000
  const int E = in_sizes[2] / 2;  // 1600000
  const int* row = edge;
  const int* col = edge + E;

  const int NBUK = (N + 511) >> 9;          // 196 buckets of 512 nodes
  const int CH = (E + G1 - 1) / G1;         // edges per partition block

  // workspace layout (16B-aligned packed arrays first).
  // Apack (N*96 uints) aliases pout/pin: pout/pin die after bucket_fill,
  // Apack is written by gather_kernel afterwards (2E = 3.2M < N*96 = 9.6M).
  uint* xp       = (uint*)d_ws;                    // N*64 (unscaled half2 pack)
  uint* idx_out  = xp + (size_t)N * D;             // E
  uint* idx_in   = idx_out + E;                    // E
  uint* Apack    = idx_in + E;                     // N*96  (f16 [N][192])
  uint* pout     = Apack;                          // E   (aliased, dead early)
  uint* pin      = pout + E;                       // E   (aliased, dead early)
  uint4* Bfrag   = (uint4*)(Apack + (size_t)N * 96);  // 2048 uint4 = 32 KB
  int* Tcnt      = (int*)(Bfrag + 2048);           // 2*NBUK (atomic totals)
  int* Bb_out    = Tcnt + 2 * NBUK;                // NBUK+1
  int* Bb_in     = Bb_out + NBUK + 1;              // NBUK+1
  int* Ccur      = Bb_in + NBUK + 1;               // 2*NBUK (atomic cursors)
  int* ofs_out   = Ccur + 2 * NBUK;                // N+1
  int* ofs_in    = ofs_out + N + 1;                // N+1
  float* inv_out = (float*)(ofs_in + N + 1);       // N
  float* inv_in  = inv_out + N;                    // N
  float* cR      = inv_in + N;                     // 64
  float* cI      = cR + 64;                        // 64

  float* out_real = (float*)d_out;
  float* out_imag = out_real + (size_t)N * D;

  // zero the atomic bucket totals, then count
  hipMemsetAsync(Tcnt, 0, 2 * NBUK * sizeof(int), stream);
  part_count<<<G1, 256, 0, stream>>>(row, col, Tcnt, E, NBUK, CH);

  // fused: bucket-base scan + cursor seed + weight collapse + B-fragments
  prep_kernel<<<1, 1024, 0, stream>>>(W_real, b_real, W_imag, b_imag, Tcnt,
                                      Bfrag, cR, cI, Bb_out, Bb_in, Ccur, E, NBUK);

  // unscaled feature pack (independent of the edge chain)
  pack_kernel<<<(N * 16 + 255) / 256, 256, 0, stream>>>(x_real, x_imag, xp, N * 16);

  // scatter edges into bucket regions (atomic range reservation)
  part_scatter<<<G1, 256, 0, stream>>>(row, col, Ccur, pout, pin, E, NBUK, CH);

  // per-bucket degrees -> ofs/inv via local scan (no global scan chain)
  offsets_kernel<<<dim3(NBUK, 2), 256, 0, stream>>>(pout, pin, Bb_out, Bb_in,
                                                    ofs_out, ofs_in, inv_out, inv_in,
                                                    E, NBUK, N);

  // per-bucket CSR fill (block-private windows; packs inv scale into idx)
  bucket_fill<<<dim3(NBUK, 2), 256, 0, stream>>>(pout, pin, Bb_out, Bb_in,
                                                 ofs_out, ofs_in, inv_out, inv_in,
                                                 idx_out, idx_in, E, NBUK, N);

  // sparse gather -> Apack (overwrites pout/pin, now dead)
  gather_kernel<<<4096, 256, 0, stream>>>((const uint4*)xp, idx_out, idx_in,
                                          ofs_out, ofs_in, inv_out, inv_in, Apack, N);
  // dense epilogue: MFMA GEMM
  gemm_kernel<<<512, 256, 0, stream>>>((const ushort*)Apack, Bfrag, cR, cI,
                                       out_real, out_imag, N);
}